// Round 2
// baseline (231.613 us; speedup 1.0000x reference)
//
#include <hip/hip_runtime.h>
#include <hip/hip_fp16.h>
#include <math.h>

// Problem constants (fixed by setup_inputs)
#define B_    2
#define L_    4096
#define H_    8
#define D_    64
#define S_    45      // sample_k
#define NT_   45      // n_top
#define BH_   16      // B*H
#define CHV   64      // cumsum chunk length
#define NCHV  64      // L_/CHV
#define KC    128     // attention key-chunk length
#define NKC   32      // L_/KC
#define SCALE 0.125f  // 1/sqrt(64)
#define NEG_BIG (-1e30f)
#define CAP   192     // candidate-set capacity for exact recheck

// Workspace layout (float element offsets; ints share the same 4B slots).
#define OFF_M     0         // 65536 floats: Mtilde[bh][q] (fp16-screened)
#define OFF_MTOP  65536     // 720 ints:    M_top[bh][u]
#define OFF_MPART 66304     // 23040 floats: m partial [bh][u][kc]
#define OFF_SPART 89344     // 23040 floats: sumexp partial [bh][u][kc]
#define OFF_CTXP  112384    // 1474560 floats: ctx partial [bh][kc][u][d]
#define OFF_VSUM  112384    // 65536 floats: vsum[bh][ch][d] (overlays CTXP)
#define OFF_EPS   1586944   // 65536 floats: eps[bh][q] certified bound
// fp16 K copy lives in `out` (16.8MB >= 8.4MB); k2's cumsum overwrites it later.

// DPP row-rotate combine within a 16-lane row (VALU-pipe, no ds_swizzle)
template <int CTRL>
__device__ __forceinline__ float dpp_ror_f(float x) {
    int y = __builtin_amdgcn_update_dpp(0, __float_as_int(x), CTRL, 0xF, 0xF, false);
    return __int_as_float(y);
}

// bf16 <-> f32 bit tricks (bf16 = high 16 bits of fp32; truncation rounding)
__device__ __forceinline__ unsigned short f2bf(float x) {
    return (unsigned short)(__float_as_uint(x) >> 16);
}
__device__ __forceinline__ float bflo(unsigned u) { return __uint_as_float(u << 16); }
__device__ __forceinline__ float bfhi(unsigned u) { return __uint_as_float(u & 0xffff0000u); }

// ---------------------------------------------------------------------------
// k0: K fp32 -> fp16 (RTN) into `out` used as scratch. 4.19M elems, 8/thread.
// ---------------------------------------------------------------------------
__global__ __launch_bounds__(256) void k0(const float* __restrict__ K,
                                          unsigned short* __restrict__ K16)
{
    int t = blockIdx.x * 256 + threadIdx.x;      // 524288 threads
    const float4* src = (const float4*)K + (long)t * 2;
    float4 a = src[0], b = src[1];
    __half2 p0 = __floats2half2_rn(a.x, a.y);
    __half2 p1 = __floats2half2_rn(a.z, a.w);
    __half2 p2 = __floats2half2_rn(b.x, b.y);
    __half2 p3 = __floats2half2_rn(b.z, b.w);
    uint4 o;
    o.x = *(unsigned*)&p0; o.y = *(unsigned*)&p1;
    o.z = *(unsigned*)&p2; o.w = *(unsigned*)&p3;
    ((uint4*)K16)[t] = o;
}

// ---------------------------------------------------------------------------
// k1: FUSED  (a) M~ screen from fp16 K (halves the L2-roofline-bound gather
//     bytes: 737->368 MB) + certified error bound eps (abs-FMA beta track).
//     Block = (b, q-quad, hh), wave = one q, XCD-slab swizzle as before.
//     Per sample one coalesced 512B gather covers 4 heads (lane = 8B chunk);
//     dot4 + beta in fp32, two 4-step DPP reduces per 16-lane head group.
//     (b) V chunk sums: blocks >= 4096 (256 blocks x 4 waves). Unchanged.
// ---------------------------------------------------------------------------
__global__ __launch_bounds__(256) void k1(const float* __restrict__ Q,
                                          const unsigned short* __restrict__ K16,
                                          const float* __restrict__ V,
                                          const int* __restrict__ samp,
                                          float* __restrict__ ws)
{
    int tid  = threadIdx.x;
    int w    = tid >> 6;          // 0..3
    int lane = tid & 63;

    if (blockIdx.x < 4096) {
        int i   = blockIdx.x;
        int xcd = i & 7;
        int b   = xcd >> 2;
        int hh  = (xcd >> 1) & 1;
        int qq  = ((i >> 3) << 1) | (xcd & 1);   // q-quad index 0..1023

        __shared__ int soff[4][S_];              // byte offsets idx*1024 | hh*512
        if (tid < 4 * S_) {
            int qs = tid / S_, ss = tid - qs * S_;
            soff[qs][ss] = (samp[(qq * 4 + qs) * S_ + ss] << 10) | (hh << 9);
        }
        __syncthreads();

        int q  = qq * 4 + w;                     // wave owns one q
        int h4 = lane >> 4;                      // head within half

        const float4 q4 = *(const float4*)(Q +
            ((((long)b * L_ + q) * H_ + hh * 4) << 6) + lane * 4);
        float aqx = fabsf(q4.x), aqy = fabsf(q4.y),
              aqz = fabsf(q4.z), aqw = fabsf(q4.w);

        const char* kslab = (const char*)K16 + (long)b * (L_ * 1024);
        unsigned lb = (unsigned)(lane * 8);

        float mx = NEG_BIG, sm = 0.f, bmx = 0.f, bsm = 0.f;
#pragma unroll
        for (int jb = 0; jb < 45; jb += 15) {    // 3 batches x 15 gathers
            uint2 kb[15];
#pragma unroll
            for (int j = 0; j < 15; ++j)
                kb[j] = *(const uint2*)(kslab +
                        ((unsigned)soff[w][jb + j] + lb));
#pragma unroll
            for (int j = 0; j < 15; ++j) {
                float2 f01 = __half22float2(*(const __half2*)&kb[j].x);
                float2 f23 = __half22float2(*(const __half2*)&kb[j].y);
                float p = q4.x * f01.x + q4.y * f01.y +
                          q4.z * f23.x + q4.w * f23.y;
                float bb = aqx * fabsf(f01.x) + aqy * fabsf(f01.y) +
                           aqz * fabsf(f23.x) + aqw * fabsf(f23.y);
                p += dpp_ror_f<0x121>(p);
                p += dpp_ror_f<0x122>(p);
                p += dpp_ror_f<0x124>(p);
                p += dpp_ror_f<0x128>(p);        // 16-lane row sum
                bb += dpp_ror_f<0x121>(bb);
                bb += dpp_ror_f<0x122>(bb);
                bb += dpp_ror_f<0x124>(bb);
                bb += dpp_ror_f<0x128>(bb);
                mx = fmaxf(mx, p);
                sm += p;
                bmx = fmaxf(bmx, bb);
                bsm += bb;
            }
        }
        if ((lane & 15) == 0) {
            long o = ((long)(b * 8 + hh * 4 + h4)) * L_ + q;
            ws[OFF_M + o]   = mx - sm * (1.0f / (float)L_);
            // |M_exact - M~| <= 2^-11*(max beta + sum beta/L) (+ fp32 slack)
            ws[OFF_EPS + o] = (bmx + bsm * (1.0f / (float)L_)) *
                              (1.001f / 2048.0f) + 1e-3f;
        }
    } else {
        // V chunk sums: wave per (bh, ch), 16 loads in flight
        int unit = (blockIdx.x - 4096) * 4 + w;   // 0..1023
        int bh = unit >> 6, ch = unit & 63;
        int b = bh >> 3, h = bh & 7;
        const float* vp = V + ((((long)b * L_ + (long)ch * CHV) * H_ + h) << 6) + lane;
        float ssum = 0.f;
#pragma unroll
        for (int ib = 0; ib < CHV; ib += 16) {
            float vb[16];
#pragma unroll
            for (int j = 0; j < 16; ++j) vb[j] = vp[(long)(ib + j) * (H_ * D_)];
#pragma unroll
            for (int j = 0; j < 16; ++j) ssum += vb[j];
        }
        ws[OFF_VSUM + unit * 64 + lane] = ssum;
    }
}

// ---------------------------------------------------------------------------
// k2: FUSED  (a) certified top-45 per (b,h): blocks < 16.
//     Phase 1: lambda = 45th largest of L = M~-eps (4-wave barrier-free
//              argmax + 4-lane merge, values only).
//     Phase 2: candidate set C = { i : M~+eps >= lambda }  (provably
//              contains the exact fp32 top-45; |C| ~ 47-55).
//     Phase 3: exact fp32 re-gather+dot for C only (~2 MB), same reduction
//              order as the previous all-fp32 kernel.
//     Phase 4: top-45 over C, tie-break lowest index.
//     (b) cumsum write: blocks >= 16 (256 blocks x 4 waves). Unchanged.
// ---------------------------------------------------------------------------
__global__ __launch_bounds__(256) void k2(const float* __restrict__ Q,
                                          const float* __restrict__ Kt,
                                          const float* __restrict__ V,
                                          const int* __restrict__ samp,
                                          float* __restrict__ out,
                                          float* __restrict__ ws)
{
    int tid  = threadIdx.x;
    int w    = tid >> 6;
    int lane = tid & 63;

    if (blockIdx.x < 16) {
        int bh = blockIdx.x;
        int b = bh >> 3, h = bh & 7;
        int* Mtop = (int*)ws + OFF_MTOP + bh * NT_;

        __shared__ float lv_[4][NT_];
        __shared__ float lam_s;
        __shared__ int   wt[4];
        __shared__ int   nc_s;
        __shared__ int   Ci[CAP];
        __shared__ int   Csamp[CAP * S_];   // pre-shifted byte offs (+h*256)
        __shared__ float Cval[CAP];

        // ---- load M~ and eps (lane-major: thread owns 16 consecutive) ----
        const float4* m4 = (const float4*)(ws + OFF_M + (long)bh * L_ +
                                           w * 1024 + lane * 16);
        const float4* e4 = (const float4*)(ws + OFF_EPS + (long)bh * L_ +
                                           w * 1024 + lane * 16);
        float vals[16], u[16];
        {
            float4 ma0 = m4[0], ma1 = m4[1], ma2 = m4[2], ma3 = m4[3];
            float4 ea0 = e4[0], ea1 = e4[1], ea2 = e4[2], ea3 = e4[3];
            float mm[16] = {ma0.x,ma0.y,ma0.z,ma0.w, ma1.x,ma1.y,ma1.z,ma1.w,
                            ma2.x,ma2.y,ma2.z,ma2.w, ma3.x,ma3.y,ma3.z,ma3.w};
            float ee[16] = {ea0.x,ea0.y,ea0.z,ea0.w, ea1.x,ea1.y,ea1.z,ea1.w,
                            ea2.x,ea2.y,ea2.z,ea2.w, ea3.x,ea3.y,ea3.z,ea3.w};
#pragma unroll
            for (int j = 0; j < 16; ++j) {
                vals[j] = mm[j] - ee[j];
                u[j]    = mm[j] + ee[j];
            }
        }

        // ---- Phase 1: 45 wave-synchronous argmax rounds on L (values) ----
        float lv = NEG_BIG;
#pragma unroll
        for (int j = 0; j < 16; ++j) lv = fmaxf(lv, vals[j]);

        for (int r = 0; r < NT_; ++r) {
            float rm = lv;
            rm = fmaxf(rm, dpp_ror_f<0x121>(rm));
            rm = fmaxf(rm, dpp_ror_f<0x122>(rm));
            rm = fmaxf(rm, dpp_ror_f<0x124>(rm));
            rm = fmaxf(rm, dpp_ror_f<0x128>(rm));
            rm = fmaxf(rm, __shfl_xor(rm, 16));
            rm = fmaxf(rm, __shfl_xor(rm, 32));      // wave max
            unsigned long long bm = __ballot(lv == rm);
            int winner = __ffsll(bm) - 1;
            if (lane == 0) lv_[w][r] = rm;
            if (lane == winner) {
                bool done = false;
#pragma unroll
                for (int j = 0; j < 16; ++j)
                    if (!done && vals[j] == lv) { vals[j] = NEG_BIG; done = true; }
                lv = NEG_BIG;
#pragma unroll
                for (int j = 0; j < 16; ++j) lv = fmaxf(lv, vals[j]);
            }
        }
        __syncthreads();

        // merge 4 sorted value-lists with 4 lanes of wave 0 -> lambda
        if (w == 0) {
            int g = lane & 3;
            int p = 0;
            float hv = lv_[g][0];
            float lam = NEG_BIG;
            for (int r = 0; r < NT_; ++r) {
                float v0 = __shfl(hv, 0), v1 = __shfl(hv, 1),
                      v2 = __shfl(hv, 2), v3 = __shfl(hv, 3);
                float bv = v0; int bg = 0;
                if (v1 > bv) { bv = v1; bg = 1; }
                if (v2 > bv) { bv = v2; bg = 2; }
                if (v3 > bv) { bv = v3; bg = 3; }
                lam = bv;
                if (g == bg) {
                    ++p;
                    hv = (p < NT_) ? lv_[g][p] : NEG_BIG;
                }
            }
            if (lane == 0) lam_s = lam;
        }
        __syncthreads();
        float lam = lam_s;

        // ---- Phase 2: build candidate set C (deterministic ascending) ----
        int cnt = 0;
#pragma unroll
        for (int j = 0; j < 16; ++j) cnt += (u[j] >= lam) ? 1 : 0;
        int incl = cnt;
#pragma unroll
        for (int off = 1; off < 64; off <<= 1) {
            int t2 = __shfl_up(incl, off);
            incl += (lane >= off) ? t2 : 0;
        }
        int excl = incl - cnt;
        if (lane == 63) wt[w] = incl;
        __syncthreads();
        int woff = 0;
        for (int w2 = 0; w2 < 4; ++w2) if (w2 < w) woff += wt[w2];
        int pos = woff + excl;
#pragma unroll
        for (int j = 0; j < 16; ++j) {
            if (u[j] >= lam) {
                if (pos < CAP) Ci[pos] = w * 1024 + lane * 16 + j;
                pos++;
            }
        }
        if (tid == 0) {
            int t3 = wt[0] + wt[1] + wt[2] + wt[3];
            nc_s = (t3 > CAP) ? CAP : t3;
        }
        __syncthreads();
        int NC = nc_s;

        // ---- Phase 2.5: stage candidate sample offsets into LDS ----
        for (int t = tid; t < NC * S_; t += 256) {
            int c = t / S_, s2 = t - c * S_;
            Csamp[t] = (samp[Ci[c] * S_ + s2] << 11) + (h << 8);
        }
        __syncthreads();

        // ---- Phase 3: exact fp32 recompute for C (16-lane groups) ----
        {
            int g = tid >> 4, l16 = tid & 15;
            const char* Kb = (const char*)Kt + (long)b * (L_ * 2048);
            for (int c = g; c < NC; c += 16) {
                int qi = Ci[c];
                const float4 qv = *(const float4*)(Q +
                    ((((long)b * L_ + qi) * H_ + h) << 6) + l16 * 4);
                float mx = NEG_BIG, sm = 0.f;
                for (int ss = 0; ss < 45; ss += 9) {
                    int so[9];
#pragma unroll
                    for (int j = 0; j < 9; ++j) so[j] = Csamp[c * S_ + ss + j];
                    float4 kb[9];
#pragma unroll
                    for (int j = 0; j < 9; ++j)
                        kb[j] = *(const float4*)(Kb + so[j] + l16 * 16);
#pragma unroll
                    for (int j = 0; j < 9; ++j) {
                        float p = qv.x * kb[j].x + qv.y * kb[j].y +
                                  qv.z * kb[j].z + qv.w * kb[j].w;
                        p += dpp_ror_f<0x121>(p);
                        p += dpp_ror_f<0x122>(p);
                        p += dpp_ror_f<0x124>(p);
                        p += dpp_ror_f<0x128>(p);   // 16-lane row sum
                        mx = fmaxf(mx, p);
                        sm += p;
                    }
                }
                if (l16 == 0) Cval[c] = mx - sm * (1.0f / (float)L_);
            }
        }
        __syncthreads();

        // ---- Phase 4: top-45 over C (wave 0; lane owns 3 consecutive) ----
        if (w == 0) {
            float v3[3];
            int base = lane * 3;
#pragma unroll
            for (int j = 0; j < 3; ++j)
                v3[j] = (base + j < NC) ? Cval[base + j] : NEG_BIG;
            for (int r = 0; r < NT_; ++r) {
                float lb2 = v3[0];
                if (v3[1] > lb2) lb2 = v3[1];
                if (v3[2] > lb2) lb2 = v3[2];
                float rm = lb2;
                rm = fmaxf(rm, dpp_ror_f<0x121>(rm));
                rm = fmaxf(rm, dpp_ror_f<0x122>(rm));
                rm = fmaxf(rm, dpp_ror_f<0x124>(rm));
                rm = fmaxf(rm, dpp_ror_f<0x128>(rm));
                rm = fmaxf(rm, __shfl_xor(rm, 16));
                rm = fmaxf(rm, __shfl_xor(rm, 32));
                unsigned long long bm2 = __ballot(lb2 == rm);
                int winner = __ffsll(bm2) - 1;
                if (lane == winner) {
                    int jw = (v3[0] == rm) ? 0 : ((v3[1] == rm) ? 1 : 2);
                    Mtop[r] = Ci[base + jw];
                    v3[jw] = NEG_BIG;
                }
            }
        }
    } else {
        // cumsum write: wave per (bh, ch); prefix from vsum chunk sums
        int unit = (blockIdx.x - 16) * 4 + w;    // 0..1023
        int bh = unit >> 6, ch = unit & 63;
        int b = bh >> 3, h = bh & 7;
        int d = lane;

        float acc = 0.f;
        {
            const float* vs = ws + OFF_VSUM + (long)bh * NCHV * 64 + d;
            int c = 0;
            for (; c + 8 <= ch; c += 8) {
                float vb[8];
#pragma unroll
                for (int j = 0; j < 8; ++j) vb[j] = vs[(c + j) * 64];
#pragma unroll
                for (int j = 0; j < 8; ++j) acc += vb[j];
            }
            for (; c < ch; ++c) acc += vs[c * 64];
        }

        const float* vp = V   + ((((long)b * L_ + (long)ch * CHV) * H_ + h) << 6) + d;
        float*       op = out + ((((long)b * L_ + (long)ch * CHV) * H_ + h) << 6) + d;
#pragma unroll
        for (int ib = 0; ib < CHV; ib += 16) {
            float vb[16];
#pragma unroll
            for (int j = 0; j < 16; ++j) vb[j] = vp[(long)(ib + j) * (H_ * D_)];
#pragma unroll
            for (int j = 0; j < 16; ++j) {
                acc += vb[j];
                op[(long)(ib + j) * (H_ * D_)] = acc;
            }
        }
    }
}

// ---------------------------------------------------------------------------
// kC: attention partials. Block = (bh, kc, ug): ~23 selected queries vs one
// 128-key chunk -> 1024 blocks. K + P in LDS as BF16 (24.4 KB; selection is
// already fixed, bf16 error << threshold). Q rows via readfirstlane-uniform
// base. PV reads P as 8-wide bf16 b128 broadcast. No min-waves bound (R5
// lesson: forcing it caused scratch spills).
// ---------------------------------------------------------------------------
#define KPAD16 72   // bf16 row stride: 144B, 16B-aligned
#define NUH    23
__global__ __launch_bounds__(256) void kC(const float* __restrict__ Q,
                                          const float* __restrict__ Kt,
                                          const float* __restrict__ V,
                                          float* __restrict__ ws)
{
    __shared__ unsigned short Klds16[KC * KPAD16];  // 18432 B
    __shared__ unsigned short P16[NUH * KC];        // 5888 B
    __shared__ int qpos[NUH];

    int tid = threadIdx.x;
    int bh = blockIdx.x >> 6;
    int kc = (blockIdx.x >> 1) & 31;
    int ug = blockIdx.x & 1;
    int b = bh >> 3, h = bh & 7;
    int kbase = kc * KC;
    int u0 = ug * 23;
    int NU = ug ? 22 : 23;

    if (tid < NU) qpos[tid] = ((const int*)ws)[OFF_MTOP + bh * NT_ + tid + u0];

    // coalesced K-chunk staging: float4 global reads -> packed bf16 LDS
    {
        const float4* ksrc4 = (const float4*)(Kt + ((((long)b * L_ + kbase) * H_ + h) << 6));
#pragma unroll
        for (int i = 0; i < 8; ++i) {
            int e = i * 256 + tid;
            int r = e >> 4, c4 = e & 15;
            float4 kv = ksrc4[(long)r * (H_ * D_ / 4) + c4];
            uint2 pk;
            pk.x = (__float_as_uint(kv.x) >> 16) | (__float_as_uint(kv.y) & 0xffff0000u);
            pk.y = (__float_as_uint(kv.z) >> 16) | (__float_as_uint(kv.w) & 0xffff0000u);
            *(uint2*)&Klds16[r * KPAD16 + c4 * 4] = pk;
        }
    }
    __syncthreads();

    int k = tid & 127, uh = tid >> 7;
    int kpos = kbase + k;
    {
        float kf[64];
#pragma unroll
        for (int j = 0; j < 8; ++j) {
            uint4 U = *(const uint4*)&Klds16[k * KPAD16 + j * 8];
            kf[j*8+0] = bflo(U.x); kf[j*8+1] = bfhi(U.x);
            kf[j*8+2] = bflo(U.y); kf[j*8+3] = bfhi(U.y);
            kf[j*8+4] = bflo(U.z); kf[j*8+5] = bfhi(U.z);
            kf[j*8+6] = bflo(U.w); kf[j*8+7] = bfhi(U.w);
        }

#pragma unroll 3
        for (int j = 0; j < 12; ++j) {
            int ul = uh * 12 + j;
            if (ul > NU - 1) ul = NU - 1;          // clamp (dup write, same val)
            int qp_ = __builtin_amdgcn_readfirstlane(qpos[ul]);
            const float4* qrow = (const float4*)(Q + ((((long)b * L_ + qp_) * H_ + h) << 6));
            float a0 = 0.f, a1 = 0.f, a2 = 0.f, a3 = 0.f;
#pragma unroll
            for (int jj = 0; jj < 16; jj += 4) {
                float4 q0 = qrow[jj + 0], q1 = qrow[jj + 1];
                float4 q2 = qrow[jj + 2], q3 = qrow[jj + 3];
                a0 += q0.x * kf[jj*4+ 0] + q0.y * kf[jj*4+ 1] +
                      q0.z * kf[jj*4+ 2] + q0.w * kf[jj*4+ 3];
                a1 += q1.x * kf[jj*4+ 4] + q1.y * kf[jj*4+ 5] +
                      q1.z * kf[jj*4+ 6] + q1.w * kf[jj*4+ 7];
                a2 += q2.x * kf[jj*4+ 8] + q2.y * kf[jj*4+ 9] +
                      q2.z * kf[jj*4+10] + q2.w * kf[jj*4+11];
                a3 += q3.x * kf[jj*4+12] + q3.y * kf[jj*4+13] +
                      q3.z * kf[jj*4+14] + q3.w * kf[jj*4+15];
            }
            float sc = ((a0 + a1) + (a2 + a3)) * SCALE;
            if (kpos > qp_) sc = NEG_BIG;   // causal mask
            P16[ul * KC + k] = f2bf(sc);
        }
    }
    __syncthreads();

    int lane = tid & 63, w = tid >> 6;
    for (int ul = w; ul < NU; ul += 4) {
        float s0 = bflo(P16[ul * KC + lane]);
        float s1 = bflo(P16[ul * KC + 64 + lane]);
        float m = fmaxf(s0, s1);
#pragma unroll
        for (int off = 32; off; off >>= 1) m = fmaxf(m, __shfl_xor(m, off));
        float e0 = __expf(s0 - m), e1 = __expf(s1 - m);
        unsigned short b0 = f2bf(e0), b1 = f2bf(e1);
        P16[ul * KC + lane]      = b0;
        P16[ul * KC + 64 + lane] = b1;
        float sm = bflo(b0) + bflo(b1);
#pragma unroll
        for (int off = 32; off; off >>= 1) sm += __shfl_xor(sm, off);
        if (lane == 0) {
            ws[OFF_MPART + ((long)bh * NT_ + u0 + ul) * NKC + kc] = m;
            ws[OFF_SPART + ((long)bh * NT_ + u0 + ul) * NKC + kc] = sm;
        }
    }
    __syncthreads();

    {
        const float* vsrc = V + ((((long)b * L_ + kbase) * H_ + h) << 6);
        float ctx[6];
#pragma unroll
        for (int j = 0; j < 6; ++j) ctx[j] = 0.f;
        for (int kk8 = 0; kk8 < 16; ++kk8) {
            float v[8];
#pragma unroll
            for (int t = 0; t < 8; ++t)
                v[t] = vsrc[(long)(kk8 * 8 + t) * (H_ * D_) + lane];
#pragma unroll
            for (int j = 0; j < 6; ++j) {
                int ul = w + j * 4;
                if (ul < NU) {
                    uint4 U = *(const uint4*)&P16[ul * KC + kk8 * 8];
                    ctx[j] += bflo(U.x) * v[0] + bfhi(U.x) * v[1]
                            + bflo(U.y) * v[2] + bfhi(U.y) * v[3]
                            + bflo(U.z) * v[4] + bfhi(U.z) * v[5]
                            + bflo(U.w) * v[6] + bfhi(U.w) * v[7];
                }
            }
        }
#pragma unroll
        for (int j = 0; j < 6; ++j) {
            int ul = w + j * 4;
            if (ul < NU)
                ws[OFF_CTXP + ((long)(bh * NKC + kc) * NT_ + u0 + ul) * 64 + lane] = ctx[j];
        }
    }
}

// ---------------------------------------------------------------------------
// kD: merge chunk partials (log-sum-exp) and overwrite selected rows.
// One 64-thread block per (bh,u) unit: 720 blocks. (R1's 4-wave variant
// regressed ~3us; reverted.)
// ---------------------------------------------------------------------------
__global__ __launch_bounds__(64) void kD(float* __restrict__ out,
                                         const float* __restrict__ ws)
{
    int lane = threadIdx.x;
    int unit = blockIdx.x;
    int bh = unit / NT_, u = unit - bh * NT_;
    int b = bh >> 3, h = bh & 7;

    const float4* mp4 = (const float4*)(ws + OFF_MPART + ((long)bh * NT_ + u) * NKC);
    const float4* sp4 = (const float4*)(ws + OFF_SPART + ((long)bh * NT_ + u) * NKC);

    float mc[NKC], sc[NKC];
    float m = NEG_BIG;
#pragma unroll
    for (int c4 = 0; c4 < NKC / 4; ++c4) {
        float4 mv = mp4[c4];
        float4 sv = sp4[c4];
        mc[c4 * 4 + 0] = mv.x; mc[c4 * 4 + 1] = mv.y;
        mc[c4 * 4 + 2] = mv.z; mc[c4 * 4 + 3] = mv.w;
        sc[c4 * 4 + 0] = sv.x; sc[c4 * 4 + 1] = sv.y;
        sc[c4 * 4 + 2] = sv.z; sc[c4 * 4 + 3] = sv.w;
        m = fmaxf(m, fmaxf(fmaxf(mv.x, mv.y), fmaxf(mv.z, mv.w)));
    }
    float T = 0.f, ctx = 0.f;
#pragma unroll
    for (int c = 0; c < NKC; ++c) {
        float wgt = __expf(mc[c] - m);
        T   += sc[c] * wgt;
        ctx += ws[OFF_CTXP + ((long)(bh * NKC + c) * NT_ + u) * 64 + lane] * wgt;
    }
    int qp = ((const int*)ws)[OFF_MTOP + bh * NT_ + u];
    out[((((long)b * L_ + qp) * H_ + h) << 6) + lane] = ctx / T;
}

// ---------------------------------------------------------------------------
extern "C" void kernel_launch(void* const* d_in, const int* in_sizes, int n_in,
                              void* d_out, int out_size, void* d_ws, size_t ws_size,
                              hipStream_t stream)
{
    const float* Q    = (const float*)d_in[0];
    const float* K    = (const float*)d_in[1];
    const float* V    = (const float*)d_in[2];
    const int*   samp = (const int*)d_in[4];   // d_in[3] = attn_mask (unused)
    float* out = (float*)d_out;
    float* ws  = (float*)d_ws;

    // 0: K -> fp16 copy, staged in `out` (overwritten by k2's cumsum later)
    k0<<<2048, 256, 0, stream>>>(K, (unsigned short*)out);
    // 1: M~ screen from fp16 K + certified eps (4096 blocks) + V chunk sums
    k1<<<4352, 256, 0, stream>>>(Q, (const unsigned short*)out, V, samp, ws);
    // 2: certified top-45 w/ exact fp32 recheck (16 blocks) + cumsum write
    k2<<<272, 256, 0, stream>>>(Q, K, V, samp, out, ws);
    // 3: attention partials (16 bh x 32 key chunks x 2 u-halves)
    kC<<<1024, 256, 0, stream>>>(Q, K, V, ws);
    // 4: merge + scatter selected rows (720 x 64-thread blocks)
    kD<<<720, 64, 0, stream>>>(out, ws);
}

// Round 3
// 188.029 us; speedup vs baseline: 1.2318x; 1.2318x over previous
//
#include <hip/hip_runtime.h>
#include <math.h>

// Problem constants (fixed by setup_inputs)
#define B_    2
#define L_    4096
#define H_    8
#define D_    64
#define S_    45      // sample_k
#define NT_   45      // n_top
#define BH_   16      // B*H
#define CHV   64      // cumsum chunk length
#define NCHV  64      // L_/CHV
#define KC    128     // attention key-chunk length
#define NKC   32      // L_/KC
#define SCALE 0.125f  // 1/sqrt(64)
#define NEG_BIG (-1e30f)

// Workspace layout (float element offsets; ints share the same 4B slots).
// VSUM no longer overlays CTXP: the fused k3 reads VSUM (cumsum blocks)
// while writing CTXP (attention blocks) concurrently. Total ~6.6 MB.
#define OFF_M     0         // 65536 floats: M[bh][q]
#define OFF_MTOP  65536     // 720 ints:    M_top[bh][u]
#define OFF_MPART 66304     // 23040 floats: m partial [bh][u][kc]
#define OFF_SPART 89344     // 23040 floats: sumexp partial [bh][u][kc]
#define OFF_CTXP  112384    // 1474560 floats: ctx partial [bh][kc][u][d]
#define OFF_VSUM  1586944   // 65536 floats: vsum[bh][ch][d] (dedicated)

// DPP row-rotate combine within a 16-lane row (VALU-pipe, no ds_swizzle)
template <int CTRL>
__device__ __forceinline__ float dpp_ror_f(float x) {
    int y = __builtin_amdgcn_update_dpp(0, __float_as_int(x), CTRL, 0xF, 0xF, false);
    return __int_as_float(y);
}

// bf16 <-> f32 bit tricks (bf16 = high 16 bits of fp32; truncation rounding)
__device__ __forceinline__ unsigned short f2bf(float x) {
    return (unsigned short)(__float_as_uint(x) >> 16);
}
__device__ __forceinline__ float bflo(unsigned u) { return __uint_as_float(u << 16); }
__device__ __forceinline__ float bfhi(unsigned u) { return __uint_as_float(u & 0xffff0000u); }

// ---------------------------------------------------------------------------
// k1: FUSED  (a) M scores: blocks < 4096, block = (b, q-quad, hh), wave = one
//     q. XCD-slab swizzle (blockIdx%8 = XCD; slab (b,hh) = 4MB = one XCD L2).
//     Per sample one coalesced 1KB gather covers 4 heads (lane = 16B chunk);
//     dot4 + 4-step DPP reduce per 16-lane head group. All 45 samples in one
//     wave. fp32 throughout (R2 lesson: fp16 screen halves bytes but doubles
//     VALU + halves occupancy -> net regression; this version is at the
//     per-XCD L2 gather roofline ~2.1 TB/s/XCD).
//     (b) V chunk sums: blocks >= 4096 (256 blocks x 4 waves).
// ---------------------------------------------------------------------------
__global__ __launch_bounds__(256) void k1(const float* __restrict__ Q,
                                          const float* __restrict__ Kt,
                                          const float* __restrict__ V,
                                          const int* __restrict__ samp,
                                          float* __restrict__ ws)
{
    int tid  = threadIdx.x;
    int w    = tid >> 6;          // 0..3
    int lane = tid & 63;

    if (blockIdx.x < 4096) {
        int i   = blockIdx.x;
        int xcd = i & 7;
        int b   = xcd >> 2;
        int hh  = (xcd >> 1) & 1;
        int qq  = ((i >> 3) << 1) | (xcd & 1);   // q-quad index 0..1023

        __shared__ int soff[4][S_];              // byte offsets idx*2048 | hh*1024
        if (tid < 4 * S_) {
            int qs = tid / S_, ss = tid - qs * S_;
            soff[qs][ss] = (samp[(qq * 4 + qs) * S_ + ss] << 11) | (hh << 10);
        }
        __syncthreads();

        int q  = qq * 4 + w;                     // wave owns one q
        int h4 = lane >> 4;                      // head within half

        const float4 q4 = *(const float4*)(Q +
            ((((long)b * L_ + q) * H_ + hh * 4) << 6) + lane * 4);

        // uniform slab base (SGPR) + 32-bit per-lane voffset
        const char* kslab = (const char*)Kt + (long)b * (L_ * 2048);
        unsigned lb = (unsigned)(lane * 16);

        float mx = NEG_BIG, sm = 0.f;
#pragma unroll
        for (int jb = 0; jb < 45; jb += 15) {    // 3 batches x 15 gathers
            float4 kb[15];
#pragma unroll
            for (int j = 0; j < 15; ++j)
                kb[j] = *(const float4*)(kslab +
                        ((unsigned)soff[w][jb + j] + lb));
#pragma unroll
            for (int j = 0; j < 15; ++j) {
                float p = q4.x * kb[j].x + q4.y * kb[j].y +
                          q4.z * kb[j].z + q4.w * kb[j].w;
                p += dpp_ror_f<0x121>(p);   // ror 1
                p += dpp_ror_f<0x122>(p);   // ror 2
                p += dpp_ror_f<0x124>(p);   // ror 4
                p += dpp_ror_f<0x128>(p);   // ror 8 -> 16-lane row sum
                mx = fmaxf(mx, p);
                sm += p;
            }
        }
        if ((lane & 15) == 0)
            ws[OFF_M + ((long)(b * 8 + hh * 4 + h4)) * L_ + q] =
                mx - sm * (1.0f / (float)L_);
    } else {
        // V chunk sums: wave per (bh, ch), 16 loads in flight
        int unit = (blockIdx.x - 4096) * 4 + w;   // 0..1023
        int bh = unit >> 6, ch = unit & 63;
        int b = bh >> 3, h = bh & 7;
        const float* vp = V + ((((long)b * L_ + (long)ch * CHV) * H_ + h) << 6) + lane;
        float ssum = 0.f;
#pragma unroll
        for (int ib = 0; ib < CHV; ib += 16) {
            float vb[16];
#pragma unroll
            for (int j = 0; j < 16; ++j) vb[j] = vp[(long)(ib + j) * (H_ * D_)];
#pragma unroll
            for (int j = 0; j < 16; ++j) ssum += vb[j];
        }
        ws[OFF_VSUM + unit * 64 + lane] = ssum;
    }
}

// ---------------------------------------------------------------------------
// k2: top-45 per (b,h): 16 blocks. Each of 4 waves does a barrier-free
// iterative argmax over its 1024-element quarter (lane-major index order ->
// ballot lowest-lane = lowest index), producing a sorted 45-list in LDS;
// then a 4-lane shfl merge (g-ascending tie-break = lowest global index).
// Short exposed kernel (~5-8us); the cumsum that used to hide it now
// overlaps kC in k3 instead (bigger win).
// ---------------------------------------------------------------------------
__global__ __launch_bounds__(256) void k2(float* __restrict__ ws)
{
    int tid  = threadIdx.x;
    int w    = tid >> 6;
    int lane = tid & 63;

    int bh = blockIdx.x;
    int* Mtop = (int*)ws + OFF_MTOP + bh * NT_;

    __shared__ float lv_[4][NT_];
    __shared__ int   li_[4][NT_];

    // load 16 consecutive M values per lane (lane-major ordering)
    const float4* m4 = (const float4*)(ws + OFF_M + (long)bh * L_ +
                                       w * 1024 + lane * 16);
    float vals[16];
    {
        float4 a = m4[0], bq = m4[1], c = m4[2], d = m4[3];
        vals[0]=a.x; vals[1]=a.y; vals[2]=a.z; vals[3]=a.w;
        vals[4]=bq.x; vals[5]=bq.y; vals[6]=bq.z; vals[7]=bq.w;
        vals[8]=c.x; vals[9]=c.y; vals[10]=c.z; vals[11]=c.w;
        vals[12]=d.x; vals[13]=d.y; vals[14]=d.z; vals[15]=d.w;
    }
    float lv = NEG_BIG; int li = lane * 16;
#pragma unroll
    for (int j = 0; j < 16; ++j)
        if (vals[j] > lv) { lv = vals[j]; li = lane * 16 + j; }

    // 45 wave-synchronous argmax rounds (no barriers)
    for (int r = 0; r < NT_; ++r) {
        float rm = lv;
        rm = fmaxf(rm, dpp_ror_f<0x121>(rm));
        rm = fmaxf(rm, dpp_ror_f<0x122>(rm));
        rm = fmaxf(rm, dpp_ror_f<0x124>(rm));
        rm = fmaxf(rm, dpp_ror_f<0x128>(rm));
        rm = fmaxf(rm, __shfl_xor(rm, 16));
        rm = fmaxf(rm, __shfl_xor(rm, 32));      // wave max in all lanes
        unsigned long long bm = __ballot(lv == rm);
        int winner = __ffsll(bm) - 1;            // lowest lane = lowest idx
        int wi = __shfl(li, winner);
        if (lane == 0) { lv_[w][r] = rm; li_[w][r] = w * 1024 + wi; }
        if (lane == winner) {
#pragma unroll
            for (int j = 0; j < 16; ++j)
                if (j == (wi & 15)) vals[j] = NEG_BIG;
            lv = NEG_BIG; li = lane * 16;
#pragma unroll
            for (int j = 0; j < 16; ++j)
                if (vals[j] > lv) { lv = vals[j]; li = lane * 16 + j; }
        }
    }
    __syncthreads();

    // merge 4 sorted lists with 4 lanes of wave 0
    if (w == 0) {
        int g = lane & 3;
        int p = 0;
        float hv = lv_[g][0]; int hi = li_[g][0];
        for (int r = 0; r < NT_; ++r) {
            float v0 = __shfl(hv, 0), v1 = __shfl(hv, 1),
                  v2 = __shfl(hv, 2), v3 = __shfl(hv, 3);
            int   i0 = __shfl(hi, 0), i1 = __shfl(hi, 1),
                  i2 = __shfl(hi, 2), i3 = __shfl(hi, 3);
            // g-ascending scan with strict > : tie -> lower g -> lower idx
            float bv = v0; int bi = i0, bg = 0;
            if (v1 > bv) { bv = v1; bi = i1; bg = 1; }
            if (v2 > bv) { bv = v2; bi = i2; bg = 2; }
            if (v3 > bv) { bv = v3; bi = i3; bg = 3; }
            if (lane == 0) Mtop[r] = bi;
            if (g == bg) {
                ++p;
                hv = (p < NT_) ? lv_[g][p] : NEG_BIG;
                hi = (p < NT_) ? li_[g][p] : 0;
            }
        }
    }
}

// ---------------------------------------------------------------------------
// k3: FUSED  (a) attention partials: blocks < 1024, block = (bh, kc, ug):
//     ~23 selected queries vs one 128-key chunk. K + P in LDS as BF16
//     (24.4 KB; selection is already fixed, bf16 error << threshold).
//     (b) cumsum write: blocks >= 1024 (256 blocks x 4 waves).
//     (a) is compute-bound (4096 waves of FMA streams), (b) is latency-bound
//     (1024 waves, strided 256B walks) and independent of (a) -> co-residency
//     hides (b)'s exposed latency under (a)'s VALU work. Previously these ran
//     serially (~40us each); fused target ~ max of the two.
// ---------------------------------------------------------------------------
#define KPAD16 72   // bf16 row stride: 144B, 16B-aligned
#define NUH    23
__global__ __launch_bounds__(256) void k3(const float* __restrict__ Q,
                                          const float* __restrict__ Kt,
                                          const float* __restrict__ V,
                                          float* __restrict__ out,
                                          float* __restrict__ ws)
{
    __shared__ unsigned short Klds16[KC * KPAD16];  // 18432 B
    __shared__ unsigned short P16[NUH * KC];        // 5888 B
    __shared__ int qpos[NUH];

    int tid = threadIdx.x;

    if (blockIdx.x < 1024) {
        int bh = blockIdx.x >> 6;
        int kc = (blockIdx.x >> 1) & 31;
        int ug = blockIdx.x & 1;
        int b = bh >> 3, h = bh & 7;
        int kbase = kc * KC;
        int u0 = ug * 23;
        int NU = ug ? 22 : 23;

        if (tid < NU) qpos[tid] = ((const int*)ws)[OFF_MTOP + bh * NT_ + tid + u0];

        // coalesced K-chunk staging: float4 global reads -> packed bf16 LDS
        {
            const float4* ksrc4 = (const float4*)(Kt + ((((long)b * L_ + kbase) * H_ + h) << 6));
#pragma unroll
            for (int i = 0; i < 8; ++i) {
                int e = i * 256 + tid;
                int r = e >> 4, c4 = e & 15;
                float4 kv = ksrc4[(long)r * (H_ * D_ / 4) + c4];
                uint2 pk;
                pk.x = (__float_as_uint(kv.x) >> 16) | (__float_as_uint(kv.y) & 0xffff0000u);
                pk.y = (__float_as_uint(kv.z) >> 16) | (__float_as_uint(kv.w) & 0xffff0000u);
                *(uint2*)&Klds16[r * KPAD16 + c4 * 4] = pk;
            }
        }
        __syncthreads();

        int k = tid & 127, uh = tid >> 7;
        int kpos = kbase + k;
        {
            float kf[64];
#pragma unroll
            for (int j = 0; j < 8; ++j) {
                uint4 U = *(const uint4*)&Klds16[k * KPAD16 + j * 8];
                kf[j*8+0] = bflo(U.x); kf[j*8+1] = bfhi(U.x);
                kf[j*8+2] = bflo(U.y); kf[j*8+3] = bfhi(U.y);
                kf[j*8+4] = bflo(U.z); kf[j*8+5] = bfhi(U.z);
                kf[j*8+6] = bflo(U.w); kf[j*8+7] = bfhi(U.w);
            }

#pragma unroll 3
            for (int j = 0; j < 12; ++j) {
                int ul = uh * 12 + j;
                if (ul > NU - 1) ul = NU - 1;      // clamp (dup write, same val)
                int qp_ = __builtin_amdgcn_readfirstlane(qpos[ul]);
                const float4* qrow = (const float4*)(Q + ((((long)b * L_ + qp_) * H_ + h) << 6));
                float a0 = 0.f, a1 = 0.f, a2 = 0.f, a3 = 0.f;
#pragma unroll
                for (int jj = 0; jj < 16; jj += 4) {
                    float4 q0 = qrow[jj + 0], q1 = qrow[jj + 1];
                    float4 q2 = qrow[jj + 2], q3 = qrow[jj + 3];
                    a0 += q0.x * kf[jj*4+ 0] + q0.y * kf[jj*4+ 1] +
                          q0.z * kf[jj*4+ 2] + q0.w * kf[jj*4+ 3];
                    a1 += q1.x * kf[jj*4+ 4] + q1.y * kf[jj*4+ 5] +
                          q1.z * kf[jj*4+ 6] + q1.w * kf[jj*4+ 7];
                    a2 += q2.x * kf[jj*4+ 8] + q2.y * kf[jj*4+ 9] +
                          q2.z * kf[jj*4+10] + q2.w * kf[jj*4+11];
                    a3 += q3.x * kf[jj*4+12] + q3.y * kf[jj*4+13] +
                          q3.z * kf[jj*4+14] + q3.w * kf[jj*4+15];
                }
                float sc = ((a0 + a1) + (a2 + a3)) * SCALE;
                if (kpos > qp_) sc = NEG_BIG;   // causal mask
                P16[ul * KC + k] = f2bf(sc);
            }
        }
        __syncthreads();

        int lane = tid & 63, w = tid >> 6;
        for (int ul = w; ul < NU; ul += 4) {
            float s0 = bflo(P16[ul * KC + lane]);
            float s1 = bflo(P16[ul * KC + 64 + lane]);
            float m = fmaxf(s0, s1);
#pragma unroll
            for (int off = 32; off; off >>= 1) m = fmaxf(m, __shfl_xor(m, off));
            float e0 = __expf(s0 - m), e1 = __expf(s1 - m);
            unsigned short b0 = f2bf(e0), b1 = f2bf(e1);
            P16[ul * KC + lane]      = b0;
            P16[ul * KC + 64 + lane] = b1;
            float sm = bflo(b0) + bflo(b1);
#pragma unroll
            for (int off = 32; off; off >>= 1) sm += __shfl_xor(sm, off);
            if (lane == 0) {
                ws[OFF_MPART + ((long)bh * NT_ + u0 + ul) * NKC + kc] = m;
                ws[OFF_SPART + ((long)bh * NT_ + u0 + ul) * NKC + kc] = sm;
            }
        }
        __syncthreads();

        {
            const float* vsrc = V + ((((long)b * L_ + kbase) * H_ + h) << 6);
            float ctx[6];
#pragma unroll
            for (int j = 0; j < 6; ++j) ctx[j] = 0.f;
            for (int kk8 = 0; kk8 < 16; ++kk8) {
                float v[8];
#pragma unroll
                for (int t = 0; t < 8; ++t)
                    v[t] = vsrc[(long)(kk8 * 8 + t) * (H_ * D_) + lane];
#pragma unroll
                for (int j = 0; j < 6; ++j) {
                    int ul = w + j * 4;
                    if (ul < NU) {
                        uint4 U = *(const uint4*)&P16[ul * KC + kk8 * 8];
                        ctx[j] += bflo(U.x) * v[0] + bfhi(U.x) * v[1]
                                + bflo(U.y) * v[2] + bfhi(U.y) * v[3]
                                + bflo(U.z) * v[4] + bfhi(U.z) * v[5]
                                + bflo(U.w) * v[6] + bfhi(U.w) * v[7];
                    }
                }
            }
#pragma unroll
            for (int j = 0; j < 6; ++j) {
                int ul = w + j * 4;
                if (ul < NU)
                    ws[OFF_CTXP + ((long)(bh * NKC + kc) * NT_ + u0 + ul) * 64 + lane] = ctx[j];
            }
        }
    } else {
        // cumsum write: wave per (bh, ch); prefix from vsum chunk sums
        int w    = tid >> 6;
        int lane = tid & 63;
        int unit = (blockIdx.x - 1024) * 4 + w;  // 0..1023
        int bh = unit >> 6, ch = unit & 63;
        int b = bh >> 3, h = bh & 7;
        int d = lane;

        float acc = 0.f;
        {
            const float* vs = ws + OFF_VSUM + (long)bh * NCHV * 64 + d;
            int c = 0;
            for (; c + 8 <= ch; c += 8) {
                float vb[8];
#pragma unroll
                for (int j = 0; j < 8; ++j) vb[j] = vs[(c + j) * 64];
#pragma unroll
                for (int j = 0; j < 8; ++j) acc += vb[j];
            }
            for (; c < ch; ++c) acc += vs[c * 64];
        }

        const float* vp = V   + ((((long)b * L_ + (long)ch * CHV) * H_ + h) << 6) + d;
        float*       op = out + ((((long)b * L_ + (long)ch * CHV) * H_ + h) << 6) + d;
#pragma unroll
        for (int ib = 0; ib < CHV; ib += 16) {
            float vb[16];
#pragma unroll
            for (int j = 0; j < 16; ++j) vb[j] = vp[(long)(ib + j) * (H_ * D_)];
#pragma unroll
            for (int j = 0; j < 16; ++j) {
                acc += vb[j];
                op[(long)(ib + j) * (H_ * D_)] = acc;
            }
        }
    }
}

// ---------------------------------------------------------------------------
// kD: merge chunk partials (log-sum-exp) and overwrite selected rows.
// One 64-thread block per (bh,u) unit: 720 blocks. (R1's 4-wave variant
// regressed; 64-thread form kept.)
// ---------------------------------------------------------------------------
__global__ __launch_bounds__(64) void kD(float* __restrict__ out,
                                         const float* __restrict__ ws)
{
    int lane = threadIdx.x;
    int unit = blockIdx.x;
    int bh = unit / NT_, u = unit - bh * NT_;
    int b = bh >> 3, h = bh & 7;

    const float4* mp4 = (const float4*)(ws + OFF_MPART + ((long)bh * NT_ + u) * NKC);
    const float4* sp4 = (const float4*)(ws + OFF_SPART + ((long)bh * NT_ + u) * NKC);

    float mc[NKC], sc[NKC];
    float m = NEG_BIG;
#pragma unroll
    for (int c4 = 0; c4 < NKC / 4; ++c4) {
        float4 mv = mp4[c4];
        float4 sv = sp4[c4];
        mc[c4 * 4 + 0] = mv.x; mc[c4 * 4 + 1] = mv.y;
        mc[c4 * 4 + 2] = mv.z; mc[c4 * 4 + 3] = mv.w;
        sc[c4 * 4 + 0] = sv.x; sc[c4 * 4 + 1] = sv.y;
        sc[c4 * 4 + 2] = sv.z; sc[c4 * 4 + 3] = sv.w;
        m = fmaxf(m, fmaxf(fmaxf(mv.x, mv.y), fmaxf(mv.z, mv.w)));
    }
    float T = 0.f, ctx = 0.f;
#pragma unroll
    for (int c = 0; c < NKC; ++c) {
        float wgt = __expf(mc[c] - m);
        T   += sc[c] * wgt;
        ctx += ws[OFF_CTXP + ((long)(bh * NKC + c) * NT_ + u) * 64 + lane] * wgt;
    }
    int qp = ((const int*)ws)[OFF_MTOP + bh * NT_ + u];
    out[((((long)b * L_ + qp) * H_ + h) << 6) + lane] = ctx / T;
}

// ---------------------------------------------------------------------------
extern "C" void kernel_launch(void* const* d_in, const int* in_sizes, int n_in,
                              void* d_out, int out_size, void* d_ws, size_t ws_size,
                              hipStream_t stream)
{
    const float* Q    = (const float*)d_in[0];
    const float* K    = (const float*)d_in[1];
    const float* V    = (const float*)d_in[2];
    const int*   samp = (const int*)d_in[4];   // d_in[3] = attn_mask (unused)
    float* out = (float*)d_out;
    float* ws  = (float*)d_ws;

    // 1: M scores (4096 blocks, wave = one q) + V chunk sums (256 blocks)
    k1<<<4352, 256, 0, stream>>>(Q, K, V, samp, ws);
    // 2: top-45 per (b,h) (16 blocks, short)
    k2<<<16, 256, 0, stream>>>(ws);
    // 3: attention partials (1024 blocks) overlapped with cumsum (256 blocks)
    k3<<<1280, 256, 0, stream>>>(Q, K, V, out, ws);
    // 4: merge + scatter selected rows (720 x 64-thread blocks)
    kD<<<720, 64, 0, stream>>>(out, ws);
}

// Round 4
// 187.179 us; speedup vs baseline: 1.2374x; 1.0045x over previous
//
#include <hip/hip_runtime.h>
#include <math.h>

// Problem constants (fixed by setup_inputs)
#define B_    2
#define L_    4096
#define H_    8
#define D_    64
#define S_    45      // sample_k
#define NT_   45      // n_top
#define BH_   16      // B*H
#define CHV   64      // cumsum chunk length
#define NCHV  64      // L_/CHV
#define KC    128     // attention key-chunk length (per block)
#define NKC2  64      // merge chunks of 64 keys (two per block: per-wave halves)
#define SCALE 0.125f  // 1/sqrt(64)
#define NEG_BIG (-1e30f)

// Workspace layout (float element offsets; ints share the same 4B slots).
#define OFF_M     0         // 65536 floats: M[bh][q]
#define OFF_MTOP  65536     // 720 ints:    M_top[bh][u]
#define OFF_MPART 66304     // 46080 floats: m partial [bh][u][kc2]
#define OFF_SPART 112384    // 46080 floats: sumexp partial [bh][u][kc2]
#define OFF_CTXP  158464    // 2949120 floats: ctx partial [bh][kc2][u][d]
#define OFF_VSUM  3107584   // 65536 floats: vsum[bh][ch][d]

typedef __attribute__((ext_vector_type(8))) short s8b;    // 8 bf16 (4 VGPR)
typedef __attribute__((ext_vector_type(4))) float f32x4;  // MFMA accumulator

// DPP row-rotate combine within a 16-lane row (VALU-pipe, no ds_swizzle)
template <int CTRL>
__device__ __forceinline__ float dpp_ror_f(float x) {
    int y = __builtin_amdgcn_update_dpp(0, __float_as_int(x), CTRL, 0xF, 0xF, false);
    return __int_as_float(y);
}

// bf16 <-> f32 bit tricks (bf16 = high 16 bits of fp32; truncation rounding)
__device__ __forceinline__ unsigned f2bf(float x) {
    return (__float_as_uint(x) >> 16);
}
__device__ __forceinline__ float bflo(unsigned u) { return __uint_as_float(u << 16); }
__device__ __forceinline__ float bfhi(unsigned u) { return __uint_as_float(u & 0xffff0000u); }

// ---------------------------------------------------------------------------
// k1: FUSED  (a) M scores (unchanged, at the per-XCD L2 random-line roofline:
//     ~14 64B-lines/cy/XCD). (b) V chunk sums (unchanged).
// ---------------------------------------------------------------------------
__global__ __launch_bounds__(256) void k1(const float* __restrict__ Q,
                                          const float* __restrict__ Kt,
                                          const float* __restrict__ V,
                                          const int* __restrict__ samp,
                                          float* __restrict__ ws)
{
    int tid  = threadIdx.x;
    int w    = tid >> 6;          // 0..3
    int lane = tid & 63;

    if (blockIdx.x < 4096) {
        int i   = blockIdx.x;
        int xcd = i & 7;
        int b   = xcd >> 2;
        int hh  = (xcd >> 1) & 1;
        int qq  = ((i >> 3) << 1) | (xcd & 1);   // q-quad index 0..1023

        __shared__ int soff[4][S_];              // byte offsets idx*2048 | hh*1024
        if (tid < 4 * S_) {
            int qs = tid / S_, ss = tid - qs * S_;
            soff[qs][ss] = (samp[(qq * 4 + qs) * S_ + ss] << 11) | (hh << 10);
        }
        __syncthreads();

        int q  = qq * 4 + w;                     // wave owns one q
        int h4 = lane >> 4;                      // head within half

        const float4 q4 = *(const float4*)(Q +
            ((((long)b * L_ + q) * H_ + hh * 4) << 6) + lane * 4);

        const char* kslab = (const char*)Kt + (long)b * (L_ * 2048);
        unsigned lb = (unsigned)(lane * 16);

        float mx = NEG_BIG, sm = 0.f;
#pragma unroll
        for (int jb = 0; jb < 45; jb += 15) {    // 3 batches x 15 gathers
            float4 kb[15];
#pragma unroll
            for (int j = 0; j < 15; ++j)
                kb[j] = *(const float4*)(kslab +
                        ((unsigned)soff[w][jb + j] + lb));
#pragma unroll
            for (int j = 0; j < 15; ++j) {
                float p = q4.x * kb[j].x + q4.y * kb[j].y +
                          q4.z * kb[j].z + q4.w * kb[j].w;
                p += dpp_ror_f<0x121>(p);   // ror 1
                p += dpp_ror_f<0x122>(p);   // ror 2
                p += dpp_ror_f<0x124>(p);   // ror 4
                p += dpp_ror_f<0x128>(p);   // ror 8 -> 16-lane row sum
                mx = fmaxf(mx, p);
                sm += p;
            }
        }
        if ((lane & 15) == 0)
            ws[OFF_M + ((long)(b * 8 + hh * 4 + h4)) * L_ + q] =
                mx - sm * (1.0f / (float)L_);
    } else {
        // V chunk sums: wave per (bh, ch), 16 loads in flight
        int unit = (blockIdx.x - 4096) * 4 + w;   // 0..1023
        int bh = unit >> 6, ch = unit & 63;
        int b = bh >> 3, h = bh & 7;
        const float* vp = V + ((((long)b * L_ + (long)ch * CHV) * H_ + h) << 6) + lane;
        float ssum = 0.f;
#pragma unroll
        for (int ib = 0; ib < CHV; ib += 16) {
            float vb[16];
#pragma unroll
            for (int j = 0; j < 16; ++j) vb[j] = vp[(long)(ib + j) * (H_ * D_)];
#pragma unroll
            for (int j = 0; j < 16; ++j) ssum += vb[j];
        }
        ws[OFF_VSUM + unit * 64 + lane] = ssum;
    }
}

// ---------------------------------------------------------------------------
// k2: top-45 per (b,h): 16 blocks (unchanged, proven).
// ---------------------------------------------------------------------------
__global__ __launch_bounds__(256) void k2(float* __restrict__ ws)
{
    int tid  = threadIdx.x;
    int w    = tid >> 6;
    int lane = tid & 63;

    int bh = blockIdx.x;
    int* Mtop = (int*)ws + OFF_MTOP + bh * NT_;

    __shared__ float lv_[4][NT_];
    __shared__ int   li_[4][NT_];

    const float4* m4 = (const float4*)(ws + OFF_M + (long)bh * L_ +
                                       w * 1024 + lane * 16);
    float vals[16];
    {
        float4 a = m4[0], bq = m4[1], c = m4[2], d = m4[3];
        vals[0]=a.x; vals[1]=a.y; vals[2]=a.z; vals[3]=a.w;
        vals[4]=bq.x; vals[5]=bq.y; vals[6]=bq.z; vals[7]=bq.w;
        vals[8]=c.x; vals[9]=c.y; vals[10]=c.z; vals[11]=c.w;
        vals[12]=d.x; vals[13]=d.y; vals[14]=d.z; vals[15]=d.w;
    }
    float lv = NEG_BIG; int li = lane * 16;
#pragma unroll
    for (int j = 0; j < 16; ++j)
        if (vals[j] > lv) { lv = vals[j]; li = lane * 16 + j; }

    for (int r = 0; r < NT_; ++r) {
        float rm = lv;
        rm = fmaxf(rm, dpp_ror_f<0x121>(rm));
        rm = fmaxf(rm, dpp_ror_f<0x122>(rm));
        rm = fmaxf(rm, dpp_ror_f<0x124>(rm));
        rm = fmaxf(rm, dpp_ror_f<0x128>(rm));
        rm = fmaxf(rm, __shfl_xor(rm, 16));
        rm = fmaxf(rm, __shfl_xor(rm, 32));      // wave max in all lanes
        unsigned long long bm = __ballot(lv == rm);
        int winner = __ffsll(bm) - 1;            // lowest lane = lowest idx
        int wi = __shfl(li, winner);
        if (lane == 0) { lv_[w][r] = rm; li_[w][r] = w * 1024 + wi; }
        if (lane == winner) {
#pragma unroll
            for (int j = 0; j < 16; ++j)
                if (j == (wi & 15)) vals[j] = NEG_BIG;
            lv = NEG_BIG; li = lane * 16;
#pragma unroll
            for (int j = 0; j < 16; ++j)
                if (vals[j] > lv) { lv = vals[j]; li = lane * 16 + j; }
        }
    }
    __syncthreads();

    if (w == 0) {
        int g = lane & 3;
        int p = 0;
        float hv = lv_[g][0]; int hi = li_[g][0];
        for (int r = 0; r < NT_; ++r) {
            float v0 = __shfl(hv, 0), v1 = __shfl(hv, 1),
                  v2 = __shfl(hv, 2), v3 = __shfl(hv, 3);
            int   i0 = __shfl(hi, 0), i1 = __shfl(hi, 1),
                  i2 = __shfl(hi, 2), i3 = __shfl(hi, 3);
            float bv = v0; int bi = i0, bg = 0;
            if (v1 > bv) { bv = v1; bi = i1; bg = 1; }
            if (v2 > bv) { bv = v2; bi = i2; bg = 2; }
            if (v3 > bv) { bv = v3; bi = i3; bg = 3; }
            if (lane == 0) Mtop[r] = bi;
            if (g == bg) {
                ++p;
                hv = (p < NT_) ? lv_[g][p] : NEG_BIG;
                hi = (p < NT_) ? li_[g][p] : 0;
            }
        }
    }
}

// ---------------------------------------------------------------------------
// k3: FUSED (a) attention partials, MFMA QK^T: blocks < 1024 = (bh, kc, ug).
//     Swapped S^T = K.Q^T via mfma_f32_16x16x32_bf16: wave (t = w&1 q-tile,
//     H = w>>1 key-half). Lane holds S[key][q] for 16 keys x 1 q; the 4-lane
//     group (c, hi=0..3) owns a full 64-key slice of one q-row -> softmax is
//     15 fmax + 2 shfl, fully in-register (separate softmax phase deleted).
//     K/Q staged bf16 in LDS with XOR swizzle (byte ^= (row&7)<<4) ->
//     conflict-free b128 fragment reads. Chunk granularity for the merge is
//     now 64 keys (NKC2): each wave-half writes its own m/sumexp/ctx partial.
//     PV keeps the proven broadcast-P16 scalar form, split into two halves.
//     (b) cumsum write: blocks >= 1024 (256 blocks x 4 waves). Unchanged.
// ---------------------------------------------------------------------------
#define KPAD16 72    // bf16 row stride for K/Q tiles: 144B
#define PSTR   136   // P16 row stride in shorts: 272B (16B-aligned rows)
__global__ __launch_bounds__(256) void k3(const float* __restrict__ Q,
                                          const float* __restrict__ Kt,
                                          const float* __restrict__ V,
                                          float* __restrict__ out,
                                          float* __restrict__ ws)
{
    __shared__ unsigned short Klds16[KC * KPAD16];  // 18432 B
    __shared__ unsigned short Qs16[32 * KPAD16];    // 4608 B
    __shared__ unsigned short P16[32 * PSTR];       // 8704 B
    __shared__ int qposs[32];

    int tid = threadIdx.x;

    if (blockIdx.x < 1024) {
        int bh = blockIdx.x >> 6;
        int kc = (blockIdx.x >> 1) & 31;
        int ug = blockIdx.x & 1;
        int b = bh >> 3, h = bh & 7;
        int kbase = kc * KC;
        int u0 = ug * 23;
        int NU = ug ? 22 : 23;

        // phase 0: clamped selected-q positions
        if (tid < 32) {
            int uu = tid < NU ? tid : NU - 1;
            qposs[tid] = ((const int*)ws)[OFF_MTOP + bh * NT_ + u0 + uu];
        }
        __syncthreads();

        // phase 1: stage K chunk (128 rows) and Q rows (32 slots) as bf16,
        // XOR-swizzled: 8B granule at short-index row*72 + (c4*4 ^ ((row&7)<<3))
        {
            const float4* ksrc4 = (const float4*)(Kt + ((((long)b * L_ + kbase) * H_ + h) << 6));
#pragma unroll
            for (int i = 0; i < 8; ++i) {
                int e = i * 256 + tid;
                int r = e >> 4, c4 = e & 15;
                float4 kv = ksrc4[(long)r * (H_ * D_ / 4) + c4];
                uint2 pk;
                pk.x = (__float_as_uint(kv.x) >> 16) | (__float_as_uint(kv.y) & 0xffff0000u);
                pk.y = (__float_as_uint(kv.z) >> 16) | (__float_as_uint(kv.w) & 0xffff0000u);
                *(uint2*)&Klds16[r * KPAD16 + ((c4 * 4) ^ ((r & 7) << 3))] = pk;
            }
#pragma unroll
            for (int i = 0; i < 2; ++i) {
                int e = i * 256 + tid;          // 512 units = 32 rows x 16
                int r = e >> 4, c4 = e & 15;
                int qp = qposs[r];
                const float4* qsrc4 = (const float4*)(Q + ((((long)b * L_ + qp) * H_ + h) << 6));
                float4 qv = qsrc4[c4];
                uint2 pk;
                pk.x = (__float_as_uint(qv.x) >> 16) | (__float_as_uint(qv.y) & 0xffff0000u);
                pk.y = (__float_as_uint(qv.z) >> 16) | (__float_as_uint(qv.w) & 0xffff0000u);
                *(uint2*)&Qs16[r * KPAD16 + ((c4 * 4) ^ ((r & 7) << 3))] = pk;
            }
        }
        __syncthreads();

        // phase 2: MFMA QK^T (swapped) + in-register softmax + P16/MPART
        {
            int lane = tid & 63, w = tid >> 6;
            int c = lane & 15, hi = lane >> 4;
            int t = w & 1, H = w >> 1;
            int slot = t * 16 + c;              // q-slot 0..31
            int qp = qposs[slot];

            // B-frags (Q): lane reads Q[slot][d0..d0+7], d0 = ks*32+hi*8
            s8b bq0 = *(const s8b*)&Qs16[slot * KPAD16 + ((hi * 8) ^ ((slot & 7) << 3))];
            s8b bq1 = *(const s8b*)&Qs16[slot * KPAD16 + ((32 + hi * 8) ^ ((slot & 7) << 3))];

            f32x4 acc0 = {0.f,0.f,0.f,0.f}, acc1 = acc0, acc2 = acc0, acc3 = acc0;
#define QK_TILE(MT, ACC)                                                      \
            {                                                                 \
                int kr = H * 64 + (MT) * 16 + c;                              \
                s8b a0 = *(const s8b*)&Klds16[kr * KPAD16 +                   \
                            ((hi * 8) ^ ((kr & 7) << 3))];                    \
                s8b a1 = *(const s8b*)&Klds16[kr * KPAD16 +                   \
                            ((32 + hi * 8) ^ ((kr & 7) << 3))];               \
                ACC = __builtin_amdgcn_mfma_f32_16x16x32_bf16(a0, bq0, ACC, 0, 0, 0); \
                ACC = __builtin_amdgcn_mfma_f32_16x16x32_bf16(a1, bq1, ACC, 0, 0, 0); \
            }
            QK_TILE(0, acc0)
            QK_TILE(1, acc1)
            QK_TILE(2, acc2)
            QK_TILE(3, acc3)
#undef QK_TILE

            // scale + causal mask; lane holds keys H*64 + mt*16 + hi*4 + reg
            float sv[16];
            float m = NEG_BIG;
#pragma unroll
            for (int mt = 0; mt < 4; ++mt) {
                f32x4 a = mt == 0 ? acc0 : (mt == 1 ? acc1 : (mt == 2 ? acc2 : acc3));
#pragma unroll
                for (int reg = 0; reg < 4; ++reg) {
                    float s = a[reg] * SCALE;
                    int kpos = kbase + H * 64 + mt * 16 + hi * 4 + reg;
                    if (kpos > qp) s = NEG_BIG;
                    sv[mt * 4 + reg] = s;
                    m = fmaxf(m, s);
                }
            }
            m = fmaxf(m, __shfl_xor(m, 16));
            m = fmaxf(m, __shfl_xor(m, 32));    // max over this 64-key half
            float ssum = 0.f;
#pragma unroll
            for (int j = 0; j < 16; ++j) {
                float e = __expf(sv[j] - m);
                sv[j] = e;
                ssum += e;
            }
            ssum += __shfl_xor(ssum, 16);
            ssum += __shfl_xor(ssum, 32);
            if (hi == 0 && c < NU) {
                // wave (t,H): slots t*16..t*16+15; c==slot&15, slot = t*16+c
                int sl = t * 16 + c;
                if (sl < NU) {
                    ws[OFF_MPART + ((long)bh * NT_ + u0 + sl) * NKC2 + kc * 2 + H] = m;
                    ws[OFF_SPART + ((long)bh * NT_ + u0 + sl) * NKC2 + kc * 2 + H] = ssum;
                }
            }
            // pack P (bf16, truncation) -> P16[slot][key]
#pragma unroll
            for (int mt = 0; mt < 4; ++mt) {
                uint2 pk;
                pk.x = f2bf(sv[mt * 4 + 0]) | (f2bf(sv[mt * 4 + 1]) << 16);
                pk.y = f2bf(sv[mt * 4 + 2]) | (f2bf(sv[mt * 4 + 3]) << 16);
                *(uint2*)&P16[slot * PSTR + H * 64 + mt * 16 + hi * 4] = pk;
            }
        }
        __syncthreads();

        // phase 3: PV, split into the two 64-key halves (separate partials)
        {
            int lane = tid & 63, w = tid >> 6;
            const float* vsrc = V + ((((long)b * L_ + kbase) * H_ + h) << 6);
            float c0[6], c1[6];
#pragma unroll
            for (int j = 0; j < 6; ++j) { c0[j] = 0.f; c1[j] = 0.f; }
            for (int kk8 = 0; kk8 < 8; ++kk8) {
                float v[8];
#pragma unroll
                for (int t = 0; t < 8; ++t)
                    v[t] = vsrc[(long)(kk8 * 8 + t) * (H_ * D_) + lane];
#pragma unroll
                for (int j = 0; j < 6; ++j) {
                    int ul = w + j * 4;
                    if (ul < NU) {
                        uint4 U = *(const uint4*)&P16[ul * PSTR + kk8 * 8];
                        c0[j] += bflo(U.x) * v[0] + bfhi(U.x) * v[1]
                               + bflo(U.y) * v[2] + bfhi(U.y) * v[3]
                               + bflo(U.z) * v[4] + bfhi(U.z) * v[5]
                               + bflo(U.w) * v[6] + bfhi(U.w) * v[7];
                    }
                }
            }
            for (int kk8 = 8; kk8 < 16; ++kk8) {
                float v[8];
#pragma unroll
                for (int t = 0; t < 8; ++t)
                    v[t] = vsrc[(long)(kk8 * 8 + t) * (H_ * D_) + lane];
#pragma unroll
                for (int j = 0; j < 6; ++j) {
                    int ul = w + j * 4;
                    if (ul < NU) {
                        uint4 U = *(const uint4*)&P16[ul * PSTR + kk8 * 8];
                        c1[j] += bflo(U.x) * v[0] + bfhi(U.x) * v[1]
                               + bflo(U.y) * v[2] + bfhi(U.y) * v[3]
                               + bflo(U.z) * v[4] + bfhi(U.z) * v[5]
                               + bflo(U.w) * v[6] + bfhi(U.w) * v[7];
                    }
                }
            }
#pragma unroll
            for (int j = 0; j < 6; ++j) {
                int ul = w + j * 4;
                if (ul < NU) {
                    ws[OFF_CTXP + ((long)(bh * NKC2 + kc * 2 + 0) * NT_ + u0 + ul) * 64 + lane] = c0[j];
                    ws[OFF_CTXP + ((long)(bh * NKC2 + kc * 2 + 1) * NT_ + u0 + ul) * 64 + lane] = c1[j];
                }
            }
        }
    } else {
        // cumsum write: wave per (bh, ch); prefix from vsum chunk sums
        int w    = tid >> 6;
        int lane = tid & 63;
        int unit = (blockIdx.x - 1024) * 4 + w;  // 0..1023
        int bh = unit >> 6, ch = unit & 63;
        int b = bh >> 3, h = bh & 7;
        int d = lane;

        float acc = 0.f;
        {
            const float* vs = ws + OFF_VSUM + (long)bh * NCHV * 64 + d;
            int c = 0;
            for (; c + 8 <= ch; c += 8) {
                float vb[8];
#pragma unroll
                for (int j = 0; j < 8; ++j) vb[j] = vs[(c + j) * 64];
#pragma unroll
                for (int j = 0; j < 8; ++j) acc += vb[j];
            }
            for (; c < ch; ++c) acc += vs[c * 64];
        }

        const float* vp = V   + ((((long)b * L_ + (long)ch * CHV) * H_ + h) << 6) + d;
        float*       op = out + ((((long)b * L_ + (long)ch * CHV) * H_ + h) << 6) + d;
#pragma unroll
        for (int ib = 0; ib < CHV; ib += 16) {
            float vb[16];
#pragma unroll
            for (int j = 0; j < 16; ++j) vb[j] = vp[(long)(ib + j) * (H_ * D_)];
#pragma unroll
            for (int j = 0; j < 16; ++j) {
                acc += vb[j];
                op[(long)(ib + j) * (H_ * D_)] = acc;
            }
        }
    }
}

// ---------------------------------------------------------------------------
// kD: merge the 64 chunk partials (log-sum-exp) and overwrite selected rows.
// One 64-thread block per (bh,u) unit: 720 blocks.
// ---------------------------------------------------------------------------
__global__ __launch_bounds__(64) void kD(float* __restrict__ out,
                                         const float* __restrict__ ws)
{
    int lane = threadIdx.x;
    int unit = blockIdx.x;
    int bh = unit / NT_, u = unit - bh * NT_;
    int b = bh >> 3, h = bh & 7;

    const float4* mp4 = (const float4*)(ws + OFF_MPART + ((long)bh * NT_ + u) * NKC2);
    const float4* sp4 = (const float4*)(ws + OFF_SPART + ((long)bh * NT_ + u) * NKC2);

    float mall[NKC2];
    float m = NEG_BIG;
#pragma unroll
    for (int c4 = 0; c4 < NKC2 / 4; ++c4) {
        float4 mv = mp4[c4];
        mall[c4 * 4 + 0] = mv.x; mall[c4 * 4 + 1] = mv.y;
        mall[c4 * 4 + 2] = mv.z; mall[c4 * 4 + 3] = mv.w;
        m = fmaxf(m, fmaxf(fmaxf(mv.x, mv.y), fmaxf(mv.z, mv.w)));
    }
    float T = 0.f, ctx = 0.f;
#pragma unroll 4
    for (int c4 = 0; c4 < NKC2 / 4; ++c4) {
        float4 sv = sp4[c4];
        float s4[4] = {sv.x, sv.y, sv.z, sv.w};
#pragma unroll
        for (int j = 0; j < 4; ++j) {
            int c = c4 * 4 + j;
            float wgt = __expf(mall[c] - m);
            T   += s4[j] * wgt;
            ctx += ws[OFF_CTXP + ((long)(bh * NKC2 + c) * NT_ + u) * 64 + lane] * wgt;
        }
    }
    int qp = ((const int*)ws)[OFF_MTOP + bh * NT_ + u];
    out[((((long)b * L_ + qp) * H_ + h) << 6) + lane] = ctx / T;
}

// ---------------------------------------------------------------------------
extern "C" void kernel_launch(void* const* d_in, const int* in_sizes, int n_in,
                              void* d_out, int out_size, void* d_ws, size_t ws_size,
                              hipStream_t stream)
{
    const float* Q    = (const float*)d_in[0];
    const float* K    = (const float*)d_in[1];
    const float* V    = (const float*)d_in[2];
    const int*   samp = (const int*)d_in[4];   // d_in[3] = attn_mask (unused)
    float* out = (float*)d_out;
    float* ws  = (float*)d_ws;

    // 1: M scores (4096 blocks, wave = one q) + V chunk sums (256 blocks)
    k1<<<4352, 256, 0, stream>>>(Q, K, V, samp, ws);
    // 2: top-45 per (b,h) (16 blocks, short)
    k2<<<16, 256, 0, stream>>>(ws);
    // 3: MFMA attention partials (1024 blocks) overlapped w/ cumsum (256)
    k3<<<1280, 256, 0, stream>>>(Q, K, V, out, ws);
    // 4: merge + scatter selected rows (720 x 64-thread blocks)
    kD<<<720, 64, 0, stream>>>(out, ws);
}